// Round 2
// baseline (892.638 us; speedup 1.0000x reference)
//
#include <hip/hip_runtime.h>
#include <hip/hip_bf16.h>

// Problem constants
#define NT 89       // n_labels
#define NB 1024     // batch
#define NE 300      // word_emb
#define EP 320      // padded e (4 n-waves x 5 frags x 16)
#define K1 1024     // ctx part of in_dim
#define NDIM 1324   // full in_dim

typedef short s8 __attribute__((ext_vector_type(8)));
typedef float f4 __attribute__((ext_vector_type(4)));

// Persistent scratch in device globals: NO dependence on ws_size.
__device__ unsigned short g_Wp[EP * K1];   // 640 KB  bf16 ctx-part of W, e-padded
__device__ float          g_M[NB * EP];    // 1.25 MB fp32 men-part + bias (t-invariant)

// Harness-verified RNE fp32->bf16 helpers.
static __device__ inline unsigned bf16r(float x) {
    unsigned u = __float_as_uint(x);
    u += 0x7FFFu + ((u >> 16) & 1u);
    return u >> 16;
}
static __device__ inline unsigned pack2(float x, float y) {
    return bf16r(x) | (bf16r(y) << 16);
}

// ---------------------------------------------------------------------------
// Pre-pass 1: pack ctx-part of W into padded bf16 image Wp[320][1024].
// ---------------------------------------------------------------------------
__global__ void pack_w_kernel(const float* __restrict__ W) {
    int idx = blockIdx.x * 256 + threadIdx.x;      // 320*1024 threads
    int e = idx >> 10, k = idx & 1023;
    float v = (e < NE) ? W[(size_t)e * NDIM + k] : 0.0f;
    g_Wp[idx] = (unsigned short)bf16r(v);
}

// ---------------------------------------------------------------------------
// Pre-pass 2: M[b][e] = bias[e] + men[b,:]·W[e,1024:1324]  (fp32-exact).
// grid (256, 5), block 256 = 64 e-threads x 4 b-rows. W/men are L2-resident.
// ---------------------------------------------------------------------------
__global__ void prep_m_kernel(const float* __restrict__ men,
                              const float* __restrict__ W,
                              const float* __restrict__ bias) {
    const int et = threadIdx.x & 63, bt = threadIdx.x >> 6;
    const int e = blockIdx.y * 64 + et;
    const int b = blockIdx.x * 4 + bt;
    float acc = 0.0f;
    if (e < NE) {
        acc = bias[e];
        const float* wr = W + (size_t)e * NDIM + K1;   // 16B-aligned
        const float* mr = men + (size_t)b * NE;        // 16B-aligned
        for (int k = 0; k < NE; k += 4) {
            float4 wv = *(const float4*)(wr + k);
            float4 mv = *(const float4*)(mr + k);
            acc += wv.x * mv.x + wv.y * mv.y + wv.z * mv.z + wv.w * mv.w;
        }
    }
    g_M[(size_t)b * EP + e] = acc;
}

// ---------------------------------------------------------------------------
// Main: scores[t][b] = sum_e relu( ctx[t,b,:]·Wc[e,:] + M[b,e] ) * types[t,e]
// Block = 128 b x 320 e for one t (ctx read ONCE). 8 waves, 2m x 4n.
// No LDS, no barriers: MFMA fragments loaded straight from global.
//   A-frag: lane(col,quad) = ctx[row=col][k=quad*8..+7]  (fp32 -> bf16 in-reg)
//   B-frag: lane(col,quad) = Wp [row=col][k=quad*8..+7]  (16B bf16 direct)
// Fragment mapping identical to the harness-verified LDS version.
// ---------------------------------------------------------------------------
__launch_bounds__(512, 2)
__global__ void scores_main_kernel(const float* __restrict__ ctx,
                                   const float* __restrict__ types,
                                   float* __restrict__ scores) {
    const int t   = blockIdx.y;
    const int b0  = blockIdx.x * 128;
    const int tid = threadIdx.x;
    const int lane = tid & 63;
    const int wave = tid >> 6;       // 0..7
    const int wm = wave >> 2;        // 0..1  (m half: 64 rows)
    const int wn = wave & 3;         // 0..3  (n quarter: 80 cols)
    const int col  = lane & 15;
    const int quad = lane >> 4;

    // Accumulators initialized from M (men-part + bias, precomputed).
    // C/D layout: out-col (e) = lane&15, out-row (b) = quad*4 + r.
    f4 acc[4][5];
    {
        const float* mbase = g_M + (size_t)(b0 + wm * 64 + quad * 4) * EP + wn * 80 + col;
        #pragma unroll
        for (int i = 0; i < 4; ++i)
            #pragma unroll
            for (int j = 0; j < 5; ++j)
                #pragma unroll
                for (int r = 0; r < 4; ++r)
                    acc[i][j][r] = mbase[(size_t)(i * 16 + r) * EP + j * 16];
    }

    // Per-lane fragment base pointers; all loop loads are base + k.
    const float* ap[4];
    #pragma unroll
    for (int i = 0; i < 4; ++i)
        ap[i] = ctx + ((size_t)t * NB + b0 + wm * 64 + i * 16 + col) * K1 + quad * 8;
    const unsigned short* bp[5];
    #pragma unroll
    for (int j = 0; j < 5; ++j)
        bp[j] = g_Wp + (size_t)(wn * 80 + j * 16 + col) * K1 + quad * 8;

    // K = 1024 in 32 steps of 32; partial unroll x8 (reg pressure / compile).
    #pragma unroll 8
    for (int kt = 0; kt < 32; ++kt) {
        const int k = kt * 32;
        s8 bf[5];
        #pragma unroll
        for (int j = 0; j < 5; ++j)
            bf[j] = *(const s8*)(bp[j] + k);
        s8 af[4];
        #pragma unroll
        for (int i = 0; i < 4; ++i) {
            float4 v0 = *(const float4*)(ap[i] + k);
            float4 v1 = *(const float4*)(ap[i] + k + 4);
            union { s8 v; unsigned u[4]; } c;
            c.u[0] = pack2(v0.x, v0.y);
            c.u[1] = pack2(v0.z, v0.w);
            c.u[2] = pack2(v1.x, v1.y);
            c.u[3] = pack2(v1.z, v1.w);
            af[i] = c.v;
        }
        #pragma unroll
        for (int i = 0; i < 4; ++i)
            #pragma unroll
            for (int j = 0; j < 5; ++j)
                acc[i][j] = __builtin_amdgcn_mfma_f32_16x16x32_bf16(af[i], bf[j], acc[i][j], 0, 0, 0);
    }

    // Epilogue: relu (bias folded into M), *types, reduce over e.
    float rowsum[4][4];
    #pragma unroll
    for (int i = 0; i < 4; ++i)
        #pragma unroll
        for (int r = 0; r < 4; ++r) rowsum[i][r] = 0.0f;

    #pragma unroll
    for (int j = 0; j < 5; ++j) {
        int e = wn * 80 + j * 16 + col;
        float tv = (e < NE) ? types[(size_t)t * NE + e] : 0.0f;
        #pragma unroll
        for (int i = 0; i < 4; ++i)
            #pragma unroll
            for (int r = 0; r < 4; ++r)
                rowsum[i][r] = fmaf(fmaxf(acc[i][j][r], 0.0f), tv, rowsum[i][r]);
    }
    #pragma unroll
    for (int i = 0; i < 4; ++i)
        #pragma unroll
        for (int r = 0; r < 4; ++r) {
            float v = rowsum[i][r];
            #pragma unroll
            for (int off = 1; off < 16; off <<= 1) v += __shfl_xor(v, off);
            if (col == 0) {
                int row = b0 + wm * 64 + i * 16 + quad * 4 + r;
                atomicAdd(&scores[(size_t)t * NB + row], v);
            }
        }
}

// ---------------------------------------------------------------------------
// WARP loss. One block per batch row i. (unchanged — verified)
// ---------------------------------------------------------------------------
__global__ void loss_kernel(const float* __restrict__ scores,
                            const int* __restrict__ target,
                            float* __restrict__ out) {
    const int i = blockIdx.x;
    const int j = threadIdx.x;   // 0..127
    __shared__ float s[NT];
    __shared__ float rw[NT];
    __shared__ int   tg[NT];
    if (j < NT) {
        s[j]  = scores[(size_t)j * NB + i];
        tg[j] = target[(size_t)i * NT + j];
        float h = 0.0f;
        for (int q = 1; q <= j; ++q) h += 1.0f / (float)q;
        rw[j] = 1.0f + (float)j + h;   // rw[j] = 1 + j + H_j
    }
    __syncthreads();

    float contrib = 0.0f;
    if (j < NT && tg[j] == 1) {
        const float sj = s[j];
        int bigger = 0;
        float msum = 0.0f;
        for (int k = 0; k < NT; ++k) {
            if (tg[k] == 0) {
                float v = 1.0f + s[k] - sj;
                if (v > 0.0f) { bigger++; msum += v; }
            }
        }
        int r = (bigger + NT - 1) % NT;   // (bigger-1) mod n, Python semantics
        contrib = rw[r] * msum;
    }
    #pragma unroll
    for (int off = 1; off < 64; off <<= 1) contrib += __shfl_xor(contrib, off);
    __shared__ float wsum[2];
    if ((threadIdx.x & 63) == 0) wsum[threadIdx.x >> 6] = contrib;
    __syncthreads();
    if (threadIdx.x == 0) atomicAdd(out, (wsum[0] + wsum[1]) * (1.0f / (float)NB));
}

// ---------------------------------------------------------------------------
extern "C" void kernel_launch(void* const* d_in, const int* in_sizes, int n_in,
                              void* d_out, int out_size, void* d_ws, size_t ws_size,
                              hipStream_t stream) {
    const float* ctx   = (const float*)d_in[0];   // (89, 1024, 1024)
    const float* men   = (const float*)d_in[1];   // (1024, 300)
    const float* types = (const float*)d_in[2];   // (89, 300)
    const float* W     = (const float*)d_in[3];   // (300, 1324)
    const float* bias  = (const float*)d_in[4];   // (300,)
    const int*   tgt   = (const int*)d_in[5];     // (1024, 89)
    float* out = (float*)d_out;

    float* scores = (float*)d_ws;                 // 89*1024 f32 (as verified kernel)

    (void)hipMemsetAsync(d_out, 0, sizeof(float), stream);
    (void)hipMemsetAsync(scores, 0, (size_t)NT * NB * sizeof(float), stream);
    hipLaunchKernelGGL(pack_w_kernel, dim3((EP * K1) / 256), dim3(256), 0, stream, W);
    hipLaunchKernelGGL(prep_m_kernel, dim3(NB / 4, EP / 64), dim3(256), 0, stream,
                       men, W, bias);
    hipLaunchKernelGGL(scores_main_kernel, dim3(NB / 128, NT), dim3(512), 0, stream,
                       ctx, types, scores);
    hipLaunchKernelGGL(loss_kernel, dim3(NB), dim3(128), 0, stream,
                       scores, tgt, out);
}